// Round 7
// baseline (413.057 us; speedup 1.0000x reference)
//
#include <hip/hip_runtime.h>
#include <hip/hip_bf16.h>

#define H    128
#define HIN  384
#define FIN  512      // H + HIN
#define KNB  48
#define DFF  512
#define NNODES 8192
#define NNB_F (KNB*HIN)   // floats of h_E per node
#define NROWS (NNODES*KNB) // 393216 message rows

typedef float f32x4 __attribute__((ext_vector_type(4)));
typedef short bf16x8 __attribute__((ext_vector_type(8)));

__device__ __forceinline__ short bfs(float x){
  __hip_bfloat16 h = __float2bfloat16(x);   // RNE
  return *(short*)&h;
}

__device__ __forceinline__ bf16x8 pack8(float4 a, float4 b){
  bf16x8 o;
  o[0]=bfs(a.x); o[1]=bfs(a.y); o[2]=bfs(a.z); o[3]=bfs(a.w);
  o[4]=bfs(b.x); o[5]=bfs(b.y); o[6]=bfs(b.z); o[7]=bfs(b.w);
  return o;
}

// fast gelu: tanh form, one v_exp_f32 + v_rcp_f32.
__device__ __forceinline__ float gelu_f(float x){
  float x2 = x*x;
  float z  = x * fmaf(0.0713548162726f, x2, 1.59576912161f);
  z = fminf(fmaxf(z, -30.f), 30.f);
  float e = __expf(z);
  return x * e * __builtin_amdgcn_rcpf(1.f + e);
}

__device__ __forceinline__ f32x4 zero4(){ f32x4 z; z[0]=0.f;z[1]=0.f;z[2]=0.f;z[3]=0.f; return z; }

// ---------------- kernel 0: convert weights fp32 -> bf16 into ws ----------------
__global__ __launch_bounds__(256) void k_convert(
    const float* __restrict__ W1, const float* __restrict__ W2,
    const float* __restrict__ W3, const float* __restrict__ Win,
    const float* __restrict__ Wout, unsigned short* __restrict__ dst)
{
  int i0 = (blockIdx.x*256 + threadIdx.x)*4;
  #pragma unroll
  for (int t=0;t<4;t++){
    int idx = i0 + t;
    float v;
    if      (idx <  65536) v = W1[idx];
    else if (idx <  81920) v = W2[idx-65536];
    else if (idx <  98304) v = W3[idx-81920];
    else if (idx < 163840) v = Win[idx-98304];
    else                   v = Wout[idx-163840];
    dst[idx] = (unsigned short)bfs(v);
  }
}

// ---------------- kernel 1: bias1[node][o] = h_V @ W1[:, :128]^T + W1_b ----------------
__global__ __launch_bounds__(256) void k_bias1(
    const float* __restrict__ hV, const unsigned short* __restrict__ wW1,
    const float* __restrict__ W1b, float* __restrict__ bias1)
{
  int tid = threadIdx.x;
  int wid = tid>>6, lane = tid&63;
  int lr = lane&15, lg = lane>>4;
  int m0 = (blockIdx.x*4 + wid)*16;

  f32x4 acc[8];
  #pragma unroll
  for (int i=0;i<8;i++) acc[i] = zero4();

  #pragma unroll
  for (int ks=0; ks<4; ks++){
    const float* p = hV + (size_t)(m0+lr)*H + ks*32 + lg*8;
    bf16x8 a = pack8(*(const float4*)p, *(const float4*)(p+4));
    #pragma unroll
    for (int nt=0; nt<8; nt++){
      bf16x8 b = *(const bf16x8*)(wW1 + (size_t)(nt*16+lr)*FIN + ks*32 + lg*8);
      acc[nt] = __builtin_amdgcn_mfma_f32_16x16x32_bf16(a, b, acc[nt], 0,0,0);
    }
  }
  #pragma unroll
  for (int nt=0; nt<8; nt++){
    int col = nt*16 + lr;
    float bv = W1b[col];
    #pragma unroll
    for (int e=0;e<4;e++){
      int row = lg*4 + e;
      bias1[(size_t)(m0+row)*H + col] = acc[nt][e] + bv;
    }
  }
}

// ---------------- kernel 2a: G1 = gelu(h_E @ W1e^T + bias1[row/48])  (giant streaming GEMM) ----------------
// grid = 3072 blocks x 512 threads (8 waves). BM=128 rows, N=128, K=384 in 6 chunks of 64.
// LDS: double-buffered bf16 A-chunk [128][72-pad] x2 = 36.9KB; 1 barrier per chunk.
__global__ __launch_bounds__(512,6) void k_gemm1(
    const float* __restrict__ hE, const unsigned short* __restrict__ wW1,
    const float* __restrict__ bias1, unsigned short* __restrict__ G1)
{
  __shared__ __align__(16) unsigned short sA[2][128*72];

  int tid = threadIdx.x;
  int wid = tid>>6, lane = tid&63;
  int lr = lane&15, lg = lane>>4;
  size_t rowbase = (size_t)blockIdx.x * 128;

  // stage addressing: 2 units/thread (unit = 8 floats), unit u = tid + 512*i
  const float* srcp[2];
  int ldst[2];
  #pragma unroll
  for (int i=0;i<2;i++){
    int u = tid + 512*i;
    int row = u>>3, cg = u&7;
    unsigned grow = (unsigned)(rowbase + row);
    unsigned node = grow/48u, nbr = grow - node*48u;
    srcp[i] = hE + (size_t)node*NNB_F + (size_t)nbr*HIN + cg*8;
    ldst[i] = row*72 + cg*8;
  }

  // prologue: stage chunk 0
  {
    float4 a0[2], a1[2];
    #pragma unroll
    for (int i=0;i<2;i++){ a0[i]=*(const float4*)(srcp[i]); a1[i]=*(const float4*)(srcp[i]+4); }
    #pragma unroll
    for (int i=0;i<2;i++) *(bf16x8*)(&sA[0][ldst[i]]) = pack8(a0[i], a1[i]);
  }
  __syncthreads();

  f32x4 acc[8];
  #pragma unroll
  for (int nt=0;nt<8;nt++) acc[nt] = zero4();

  for (int c=0;c<6;c++){
    float4 a0[2], a1[2];
    if (c<5){
      #pragma unroll
      for (int i=0;i<2;i++){
        const float* p = srcp[i] + (c+1)*64;
        a0[i]=*(const float4*)p; a1[i]=*(const float4*)(p+4);
      }
    }
    const unsigned short* buf = &sA[c&1][0];
    #pragma unroll
    for (int ks=0;ks<2;ks++){
      bf16x8 af = *(const bf16x8*)(buf + (wid*16+lr)*72 + ks*32 + lg*8);
      #pragma unroll
      for (int nt=0;nt<8;nt++){
        bf16x8 b = *(const bf16x8*)(wW1 + (size_t)(nt*16+lr)*FIN + (H + c*64 + ks*32 + lg*8));
        acc[nt] = __builtin_amdgcn_mfma_f32_16x16x32_bf16(af, b, acc[nt], 0,0,0);
      }
    }
    if (c<5){
      #pragma unroll
      for (int i=0;i<2;i++) *(bf16x8*)(&sA[(c+1)&1][ldst[i]]) = pack8(a0[i], a1[i]);
    }
    __syncthreads();
  }

  // epilogue: + bias1[row/48][col], gelu, transpose via LDS, coalesced bf16 store
  unsigned short* sT = &sA[0][0];   // [128][136], spans both buffers (17408 <= 18432 ushorts)
  unsigned nodee[4];
  #pragma unroll
  for (int e=0;e<4;e++) nodee[e] = (unsigned)(rowbase + wid*16 + lg*4 + e)/48u;
  #pragma unroll
  for (int nt=0;nt<8;nt++){
    int col = nt*16 + lr;
    #pragma unroll
    for (int e=0;e<4;e++){
      float bv = bias1[(size_t)nodee[e]*H + col];
      float g = gelu_f(acc[nt][e] + bv);
      sT[(wid*16+lg*4+e)*136 + col] = (unsigned short)bfs(g);
    }
  }
  __syncthreads();
  #pragma unroll
  for (int i=0;i<4;i++){
    int u = tid + 512*i;             // 2048 bf16x8 units
    int row = u>>4, cg = u&15;
    *(bf16x8*)(G1 + (rowbase+row)*H + cg*8) = *(const bf16x8*)(sT + row*136 + cg*8);
  }
}

// ---------------- kernel 2b: per-96-row tile (2 nodes): GEMM2 -> gelu -> GEMM3 -> mask+segsum -> LN1 ----------------
// grid = 4096 blocks x 256 threads (4 waves). LDS 27.2KB.
__global__ __launch_bounds__(256,4) void k_msg23(
    const unsigned short* __restrict__ G1,
    const unsigned short* __restrict__ wW2, const unsigned short* __restrict__ wW3,
    const float* __restrict__ W2b, const float* __restrict__ W3b,
    const float* __restrict__ maskA, const float* __restrict__ hV,
    const float* __restrict__ ln1w, const float* __restrict__ ln1b,
    float* __restrict__ hmid)
{
  __shared__ __align__(16) unsigned short sG[96*136];
  __shared__ float sDh[2][128];

  int tid = threadIdx.x;
  int wid = tid>>6, lane = tid&63;
  int lr = lane&15, lg = lane>>4;
  size_t rbase = (size_t)blockIdx.x * 96;

  // stage G1 tile [96][128] bf16 -> LDS
  #pragma unroll
  for (int i=0;i<6;i++){
    int u = tid + 256*i;             // 1536 units
    int row = u>>4, cg = u&15;
    *(bf16x8*)(sG + row*136 + cg*8) = *(const bf16x8*)(G1 + (rbase+row)*H + cg*8);
  }
  __syncthreads();

  // GEMM2: [96x128] @ W2^T, wave handles nt = wid*2+j, mt = 0..5
  f32x4 acc2[6][2];
  #pragma unroll
  for (int mt=0;mt<6;mt++){ acc2[mt][0]=zero4(); acc2[mt][1]=zero4(); }
  #pragma unroll
  for (int ks=0;ks<4;ks++){
    bf16x8 a[6];
    #pragma unroll
    for (int mt=0;mt<6;mt++)
      a[mt] = *(const bf16x8*)(sG + (mt*16+lr)*136 + ks*32 + lg*8);
    #pragma unroll
    for (int j=0;j<2;j++){
      int nt = wid*2 + j;
      bf16x8 b = *(const bf16x8*)(wW2 + (size_t)(nt*16+lr)*H + ks*32 + lg*8);
      #pragma unroll
      for (int mt=0;mt<6;mt++)
        acc2[mt][j] = __builtin_amdgcn_mfma_f32_16x16x32_bf16(a[mt], b, acc2[mt][j], 0,0,0);
    }
  }
  __syncthreads();   // all G1 reads done

  // ep2: + b2, gelu -> overwrite sG
  #pragma unroll
  for (int j=0;j<2;j++){
    int col = (wid*2+j)*16 + lr;
    float bv = W2b[col];
    #pragma unroll
    for (int mt=0;mt<6;mt++)
      #pragma unroll
      for (int e=0;e<4;e++){
        float g = gelu_f(acc2[mt][j][e] + bv);
        sG[(mt*16+lg*4+e)*136 + col] = (unsigned short)bfs(g);
      }
  }
  __syncthreads();

  // GEMM3: [96x128] @ W3^T
  f32x4 acc3[6][2];
  #pragma unroll
  for (int mt=0;mt<6;mt++){ acc3[mt][0]=zero4(); acc3[mt][1]=zero4(); }
  #pragma unroll
  for (int ks=0;ks<4;ks++){
    bf16x8 a[6];
    #pragma unroll
    for (int mt=0;mt<6;mt++)
      a[mt] = *(const bf16x8*)(sG + (mt*16+lr)*136 + ks*32 + lg*8);
    #pragma unroll
    for (int j=0;j<2;j++){
      int nt = wid*2 + j;
      bf16x8 b = *(const bf16x8*)(wW3 + (size_t)(nt*16+lr)*H + ks*32 + lg*8);
      #pragma unroll
      for (int mt=0;mt<6;mt++)
        acc3[mt][j] = __builtin_amdgcn_mfma_f32_16x16x32_bf16(a[mt], b, acc3[mt][j], 0,0,0);
    }
  }

  // ep3: + b3, * mask_attend, segmented column-sum (rows 0-47 -> node0, 48-95 -> node1)
  float mvv[6][4];
  #pragma unroll
  for (int mt=0;mt<6;mt++){
    int sel = (mt>=3);
    #pragma unroll
    for (int e=0;e<4;e++){
      int row = mt*16 + lg*4 + e;
      mvv[mt][e] = maskA[(size_t)(blockIdx.x*2 + sel)*KNB + (row - sel*48)];
    }
  }
  #pragma unroll
  for (int j=0;j<2;j++){
    int col = (wid*2+j)*16 + lr;
    float bv = W3b[col];
    float p0 = 0.f, p1 = 0.f;
    #pragma unroll
    for (int mt=0;mt<3;mt++)
      #pragma unroll
      for (int e=0;e<4;e++)
        p0 += (acc3[mt][j][e] + bv) * mvv[mt][e];
    #pragma unroll
    for (int mt=3;mt<6;mt++)
      #pragma unroll
      for (int e=0;e<4;e++)
        p1 += (acc3[mt][j][e] + bv) * mvv[mt][e];
    p0 += __shfl_xor(p0, 16); p0 += __shfl_xor(p0, 32);
    p1 += __shfl_xor(p1, 16); p1 += __shfl_xor(p1, 32);
    if (lane < 16){
      sDh[0][(wid*2+j)*16 + lane] = p0;
      sDh[1][(wid*2+j)*16 + lane] = p1;
    }
  }
  __syncthreads();

  // LN1: waves 0,1 each handle one node
  if (wid < 2){
    size_t node = (size_t)blockIdx.x*2 + wid;
    int c0i = lane, c1i = lane + 64;
    float t0 = hV[node*H + c0i] + sDh[wid][c0i]*(1.0f/30.0f);
    float t1 = hV[node*H + c1i] + sDh[wid][c1i]*(1.0f/30.0f);
    float s = t0 + t1, q = t0*t0 + t1*t1;
    #pragma unroll
    for (int off=1; off<64; off<<=1){ s += __shfl_xor(s, off); q += __shfl_xor(q, off); }
    float mu  = s * (1.0f/128.0f);
    float var = q * (1.0f/128.0f) - mu*mu;
    float rs  = rsqrtf(var + 1e-5f);
    hmid[node*H + c0i] = (t0-mu)*rs*ln1w[c0i] + ln1b[c0i];
    hmid[node*H + c1i] = (t1-mu)*rs*ln1w[c1i] + ln1b[c1i];
  }
}

// ---------------- kernel 3: FFN + LN2 + mask_V -> out (in place over hmid) ----------------
__global__ __launch_bounds__(256) void k_ffn(
    const float* __restrict__ hmid, const unsigned short* __restrict__ wWin,
    const unsigned short* __restrict__ wWout,
    const float* __restrict__ Winb, const float* __restrict__ Woutb,
    const float* __restrict__ ln2w, const float* __restrict__ ln2b,
    const float* __restrict__ maskV, float* __restrict__ out)
{
  __shared__ __align__(16) unsigned short sH[32*136];
  __shared__ __align__(16) unsigned short sU[32*520];
  __shared__ float sT[32*132];

  int tid = threadIdx.x;
  int m0 = blockIdx.x * 32;

  #pragma unroll
  for (int i=0;i<2;i++){
    int c = i*256 + tid;
    int row = c>>4, cir = c&15;
    const float* p = hmid + (size_t)(m0+row)*H + cir*8;
    *(bf16x8*)(sH + row*136 + cir*8) = pack8(*(const float4*)p, *(const float4*)(p+4));
  }
  __syncthreads();

  int wid = tid>>6, lane = tid&63;
  int lr = lane&15, lg = lane>>4;

  f32x4 acc[2][8];
  #pragma unroll
  for (int mt=0;mt<2;mt++)
    #pragma unroll
    for (int j=0;j<8;j++) acc[mt][j] = zero4();

  #pragma unroll
  for (int ks=0; ks<4; ks++){
    bf16x8 a[2];
    #pragma unroll
    for (int mt=0;mt<2;mt++)
      a[mt] = *(const bf16x8*)(sH + (mt*16+lr)*136 + ks*32 + lg*8);
    #pragma unroll
    for (int j=0;j<8;j++){
      int nt = wid*8 + j;
      bf16x8 b = *(const bf16x8*)(wWin + (size_t)(nt*16+lr)*H + ks*32 + lg*8);
      #pragma unroll
      for (int mt=0;mt<2;mt++)
        acc[mt][j] = __builtin_amdgcn_mfma_f32_16x16x32_bf16(a[mt], b, acc[mt][j], 0,0,0);
    }
  }
  #pragma unroll
  for (int j=0;j<8;j++){
    int col = (wid*8+j)*16 + lr;
    float bv = Winb[col];
    #pragma unroll
    for (int mt=0;mt<2;mt++){
      #pragma unroll
      for (int e=0;e<4;e++){
        float g = gelu_f(acc[mt][j][e] + bv);
        int row = mt*16 + lg*4 + e;
        sU[row*520 + col] = (unsigned short)bfs(g);
      }
    }
  }
  __syncthreads();

  f32x4 accO[2][2];
  #pragma unroll
  for (int mt=0;mt<2;mt++){ accO[mt][0]=zero4(); accO[mt][1]=zero4(); }

  for (int ks=0; ks<16; ks++){
    bf16x8 a[2];
    #pragma unroll
    for (int mt=0;mt<2;mt++)
      a[mt] = *(const bf16x8*)(sU + (mt*16+lr)*520 + ks*32 + lg*8);
    #pragma unroll
    for (int j=0;j<2;j++){
      int nt = wid*2 + j;
      bf16x8 b = *(const bf16x8*)(wWout + (size_t)(nt*16+lr)*DFF + ks*32 + lg*8);
      #pragma unroll
      for (int mt=0;mt<2;mt++)
        accO[mt][j] = __builtin_amdgcn_mfma_f32_16x16x32_bf16(a[mt], b, accO[mt][j], 0,0,0);
    }
  }
  #pragma unroll
  for (int j=0;j<2;j++){
    int col = (wid*2+j)*16 + lr;
    float bv = Woutb[col];
    #pragma unroll
    for (int mt=0;mt<2;mt++){
      #pragma unroll
      for (int e=0;e<4;e++){
        int row = mt*16 + lg*4 + e;
        float t = accO[mt][j][e] + bv + hmid[(size_t)(m0+row)*H + col];
        sT[row*132 + col] = t;
      }
    }
  }
  __syncthreads();

  int row = tid>>3, part = tid&7;
  float s=0.f, q=0.f;
  #pragma unroll
  for (int jj=0;jj<16;jj++){
    float v = sT[row*132 + part*16 + jj];
    s += v; q += v*v;
  }
  s += __shfl_xor(s,1); q += __shfl_xor(q,1);
  s += __shfl_xor(s,2); q += __shfl_xor(q,2);
  s += __shfl_xor(s,4); q += __shfl_xor(q,4);
  float mu  = s*(1.0f/128.0f);
  float var = q*(1.0f/128.0f) - mu*mu;
  float rs  = rsqrtf(var + 1e-5f);
  float mv  = maskV[m0+row];
  #pragma unroll
  for (int jj=0;jj<16;jj++){
    int c = part*16 + jj;
    out[(size_t)(m0+row)*H + c] = mv * ((sT[row*132+c]-mu)*rs*ln2w[c] + ln2b[c]);
  }
}

extern "C" void kernel_launch(void* const* d_in, const int* in_sizes, int n_in,
                              void* d_out, int out_size, void* d_ws, size_t ws_size,
                              hipStream_t stream)
{
  const float* hV    = (const float*)d_in[0];
  const float* hE    = (const float*)d_in[1];
  const float* maskV = (const float*)d_in[2];
  const float* maskA = (const float*)d_in[3];
  const float* W1w   = (const float*)d_in[4];
  const float* W1b   = (const float*)d_in[5];
  const float* W2w   = (const float*)d_in[6];
  const float* W2b   = (const float*)d_in[7];
  const float* W3w   = (const float*)d_in[8];
  const float* W3b   = (const float*)d_in[9];
  const float* ln1w  = (const float*)d_in[10];
  const float* ln1b  = (const float*)d_in[11];
  const float* Winw  = (const float*)d_in[12];
  const float* Winb  = (const float*)d_in[13];
  const float* Woutw = (const float*)d_in[14];
  const float* Woutb = (const float*)d_in[15];
  const float* ln2w  = (const float*)d_in[16];
  const float* ln2b  = (const float*)d_in[17];

  unsigned short* wAll  = (unsigned short*)d_ws;
  unsigned short* wW1   = wAll;            // [128][512] bf16
  unsigned short* wW2   = wAll + 65536;    // [128][128]
  unsigned short* wW3   = wAll + 81920;    // [128][128]
  unsigned short* wWin  = wAll + 98304;    // [512][128]
  unsigned short* wWout = wAll + 163840;   // [128][512]
  float* bias1 = (float*)((char*)d_ws + 458752);            // [8192][128] f32 (4 MB)
  unsigned short* G1 = (unsigned short*)((char*)d_ws + 4653056); // [393216][128] bf16 (100.7 MB)
  float* hmid  = (float*)d_out;            // [8192][128] f32 — reuse d_out as scratch
  float* outp  = (float*)d_out;

  k_convert<<<224, 256, 0, stream>>>(W1w, W2w, W3w, Winw, Woutw, wAll);
  k_bias1  <<<128, 256, 0, stream>>>(hV, wW1, W1b, bias1);
  k_gemm1  <<<NROWS/128, 512, 0, stream>>>(hE, wW1, bias1, G1);
  k_msg23  <<<NROWS/96, 256, 0, stream>>>(G1, wW2, wW3, W2b, W3b, maskA,
                                          hV, ln1w, ln1b, hmid);
  k_ffn    <<<NNODES/32, 256, 0, stream>>>(hmid, wWin, wWout, Winb, Woutb,
                                           ln2w, ln2b, maskV, outp);
}